// Round 12
// baseline (374.356 us; speedup 1.0000x reference)
//
#include <hip/hip_runtime.h>

// ---------- types ----------
typedef short s16x8 __attribute__((ext_vector_type(8)));
typedef float f32x4 __attribute__((ext_vector_type(4)));

__device__ __forceinline__ unsigned short f2bf(float f) {
    unsigned int u = __builtin_bit_cast(unsigned int, f);
    unsigned int r = u + 0x7FFFu + ((u >> 16) & 1u);
    return (unsigned short)(r >> 16);
}

__device__ __forceinline__ float bf2f(unsigned short h) {
    return __builtin_bit_cast(float, ((unsigned int)h) << 16);
}

__device__ __forceinline__ void gload16(const unsigned short* g, unsigned short* l) {
    __builtin_amdgcn_global_load_lds(
        (const __attribute__((address_space(1))) unsigned int*)g,
        (__attribute__((address_space(3))) unsigned int*)l, 16, 0, 0);
}

__device__ __forceinline__ s16x8 ldf(const unsigned short* p) {
    return *reinterpret_cast<const s16x8*>(p);
}

// ---------- fp32 -> bf16, two arrays in one launch ----------
__global__ __launch_bounds__(256) void cvt_bf16_2(
    const float* __restrict__ in0, unsigned short* __restrict__ out0, int n0blk, int n0,
    const float* __restrict__ in1, unsigned short* __restrict__ out1, int n1) {
    const float* in;
    unsigned short* out;
    int n, bid;
    if (blockIdx.x < n0blk) { in = in0; out = out0; n = n0; bid = blockIdx.x; }
    else { in = in1; out = out1; n = n1; bid = blockIdx.x - n0blk; }
    int nblk = (blockIdx.x < n0blk) ? n0blk : (gridDim.x - n0blk);
    int i = (bid * 256 + threadIdx.x) * 8;
    int stride = nblk * 256 * 8;
    for (; i < n; i += stride) {
        float4 a = *reinterpret_cast<const float4*>(in + i);
        float4 b = *reinterpret_cast<const float4*>(in + i + 4);
        uint4 o;
        o.x = (unsigned int)f2bf(a.x) | ((unsigned int)f2bf(a.y) << 16);
        o.y = (unsigned int)f2bf(a.z) | ((unsigned int)f2bf(a.w) << 16);
        o.z = (unsigned int)f2bf(b.x) | ((unsigned int)f2bf(b.y) << 16);
        o.w = (unsigned int)f2bf(b.z) | ((unsigned int)f2bf(b.w) << 16);
        *reinterpret_cast<uint4*>(out + i) = o;
    }
}

// ---------- batched transpose + convert: Wt[n][k] = bf16(W[k][n]), 2 matrices ----------
__global__ __launch_bounds__(256) void transpose2_bf16(
    const float* __restrict__ W0, const float* __restrict__ W1,
    unsigned short* __restrict__ T0, unsigned short* __restrict__ T1, int K, int N) {
    __shared__ float t[32][33];
    const float* W = blockIdx.z ? W1 : W0;
    unsigned short* Wt = blockIdx.z ? T1 : T0;
    int k0 = blockIdx.x * 32, n0 = blockIdx.y * 32;
    int tid = threadIdx.x;
    int r = tid >> 5, c = tid & 31;
    for (int p = 0; p < 4; ++p)
        t[p * 8 + r][c] = W[(size_t)(k0 + p * 8 + r) * N + n0 + c];
    __syncthreads();
    for (int p = 0; p < 4; ++p)
        Wt[(size_t)(n0 + p * 8 + r) * K + k0 + c] = f2bf(t[c][p * 8 + r]);
}

// ---------- GEMM (proven): 128x128, BK=64, dbuf 2-phase ----------
template <int OUTMODE>
__global__ __launch_bounds__(256, 2) void gemm_db(
    const unsigned short* __restrict__ A, const unsigned short* __restrict__ Bt,
    int M, int N, int K,
    float* __restrict__ Cf,
    unsigned short* __restrict__ outA, unsigned short* __restrict__ outVt,
    int seqlen) {
    extern __shared__ __align__(16) unsigned short smem[];
    unsigned short* As = smem;           // [2][128*64]
    unsigned short* Bs = smem + 16384;   // [2][128*64]

    int tid = threadIdx.x, wid = tid >> 6, lane = tid & 63;
    int nb = N / 128;
    int nwg = gridDim.x, bid = blockIdx.x;
    int wg = (bid & 7) * (nwg >> 3) + (bid >> 3);  // bijective XCD swizzle (nwg%8==0)
    int tm = wg / nb, tn = wg % nb;
    int m0 = tm * 128, n0 = tn * 128;
    int wm = (wid >> 1) * 64, wn = (wid & 1) * 64;
    int lrow = lane & 15, lkc = lane >> 4;

    int lrsub = lane >> 3;
    int gch = (lane & 7) ^ lrsub;
    const unsigned short* gA[4];
    const unsigned short* gB[4];
    unsigned short* lA[4];
    unsigned short* lB[4];
#pragma unroll
    for (int p = 0; p < 4; ++p) {
        int r = (wid * 4 + p) * 8 + lrsub;
        gA[p] = A + (size_t)(m0 + r) * K + gch * 8;
        gB[p] = Bt + (size_t)(n0 + r) * K + gch * 8;
        lA[p] = As + (wid * 4 + p) * 512;
        lB[p] = Bs + (wid * 4 + p) * 512;
    }

    int offA[2][4], offB[2][4];
#pragma unroll
    for (int kh = 0; kh < 2; ++kh)
#pragma unroll
        for (int i = 0; i < 4; ++i) {
            int ra = wm + i * 16 + lrow;
            offA[kh][i] = ra * 64 + (((kh * 4 + lkc) ^ (ra & 7)) * 8);
            int rb = wn + i * 16 + lrow;
            offB[kh][i] = rb * 64 + (((kh * 4 + lkc) ^ (rb & 7)) * 8);
        }

    int NT = K / 64;
    f32x4 acc[4][4] = {};

#pragma unroll
    for (int p = 0; p < 4; ++p) { gload16(gA[p], lA[p]); gload16(gB[p], lB[p]); }

    int cur = 0;
    for (int t = 0; t < NT; ++t) {
        __syncthreads();
        if (t + 1 < NT) {
            int nxt = (cur ^ 1) * 8192;
            int koff = (t + 1) * 64;
#pragma unroll
            for (int p = 0; p < 4; ++p) {
                gload16(gA[p] + koff, lA[p] + nxt);
                gload16(gB[p] + koff, lB[p] + nxt);
            }
        }
        const unsigned short* Ab = As + cur * 8192;
        const unsigned short* Bb = Bs + cur * 8192;
#pragma unroll
        for (int kh = 0; kh < 2; ++kh) {
            s16x8 af[4], bfv[4];
#pragma unroll
            for (int i = 0; i < 4; ++i) af[i] = ldf(&Ab[offA[kh][i]]);
#pragma unroll
            for (int j = 0; j < 4; ++j) bfv[j] = ldf(&Bb[offB[kh][j]]);
#pragma unroll
            for (int i = 0; i < 4; ++i)
#pragma unroll
                for (int j = 0; j < 4; ++j)
                    acc[i][j] = __builtin_amdgcn_mfma_f32_16x16x32_bf16(af[i], bfv[j], acc[i][j], 0, 0, 0);
        }
        cur ^= 1;
    }

    int orow4 = (lane >> 4) * 4;
    int bblk = (OUTMODE == 1) ? (m0 / seqlen) : 0;
    for (int i = 0; i < 4; ++i)
        for (int j = 0; j < 4; ++j)
            for (int r = 0; r < 4; ++r) {
                int row = m0 + wm + i * 16 + orow4 + r;
                int col = n0 + wn + j * 16 + lrow;
                float v = acc[i][j][r];
                if constexpr (OUTMODE == 0) {
                    Cf[(size_t)row * N + col] = v;
                } else {
                    int s = row - bblk * seqlen;
                    unsigned short hv = f2bf(v);
                    if (col < 768) {
                        int h = col / 96, d = col - h * 96;
                        outA[(((size_t)(bblk * 8 + h)) * seqlen + s) * 96 + d] = hv;
                    } else {
                        int cc = col - 768;
                        int h = cc / 96, d = cc - h * 96;
                        outVt[(((size_t)(bblk * 8 + h)) * 96 + d) * seqlen + s] = hv;
                    }
                }
            }
}

// ---------- fused masked-softmax cross-attention (T14 async-STAGE) ----------
#define MT 64
__global__ __launch_bounds__(256) void attn_kernel(
    const unsigned short* __restrict__ Qb,   // [bh][256][96]
    const unsigned short* __restrict__ Kb,   // [bh][1024][96]
    const unsigned short* __restrict__ Vt,   // [bh][96][1024]
    const int* __restrict__ drug_mask,       // [16][256]
    const int* __restrict__ pro_mask,        // [16][1024]
    float* __restrict__ attn_out,            // [bh][256][1024]
    unsigned short* __restrict__ AO)         // [4096][768]
{
    constexpr float scale = 0.10206207261596575f;  // 96^-0.5
    __shared__ __align__(16) unsigned short Qs[64][104];
    __shared__ __align__(16) unsigned short Ks[MT][104];
    __shared__ __align__(16) unsigned short Vts[96][MT + 8];
    __shared__ __align__(16) unsigned short Ps[4][16][MT + 8];
    __shared__ float colv[1024];

    int tid = threadIdx.x, wid = tid >> 6, lane = tid & 63;
    int bh = blockIdx.x, nt = blockIdx.y;
    int b = bh >> 3, h = bh & 7;
    const unsigned short* Qg = Qb + (size_t)bh * 256 * 96 + (size_t)nt * 64 * 96;
    const unsigned short* Kg = Kb + (size_t)bh * 1024 * 96;
    const unsigned short* Vg = Vt + (size_t)bh * 96 * 1024;

    for (int idx = tid; idx < 64 * 12; idx += 256) {
        int r = idx / 12, s = idx % 12;
        *reinterpret_cast<uint4*>(&Qs[r][s * 8]) =
            *reinterpret_cast<const uint4*>(&Qg[r * 96 + s * 8]);
    }
    for (int m = tid; m < 1024; m += 256)
        colv[m] = (pro_mask[b * 1024 + m] != 0) ? 1.0f : 0.0f;

    int lrow = lane & 15, lkg = lane >> 4;
    int qrow0 = nt * 64 + wid * 16;
    float rv[4];
    for (int r = 0; r < 4; ++r)
        rv[r] = (drug_mask[b * 256 + qrow0 + lkg * 4 + r] != 0) ? 1.0f : 0.0f;

    // staging coordinates (loop-invariant)
    int kr[3], kc[3], vr[3], vc[3];
#pragma unroll
    for (int p = 0; p < 3; ++p) {
        int idx = tid + p * 256;
        kr[p] = idx / 12; kc[p] = (idx % 12) * 8;   // K: 64 rows x 12 chunks
        vr[p] = idx / 8;  vc[p] = (idx % 8) * 8;    // V: 96 rows x 8 chunks
    }

    __syncthreads();
    s16x8 qa[3];
    for (int kk = 0; kk < 3; ++kk)
        qa[kk] = ldf(&Qs[wid * 16 + lrow][kk * 32 + lkg * 8]);

    float mrun[4], srun[4];
    for (int r = 0; r < 4; ++r) { mrun[r] = -3.0e38f; srun[r] = 0.f; }

    // ---- Pass A: prefetch K(t+1) under compute(t) ----
    uint4 kreg[3];
#pragma unroll
    for (int p = 0; p < 3; ++p)
        kreg[p] = *reinterpret_cast<const uint4*>(&Kg[(size_t)kr[p] * 96 + kc[p]]);

    for (int tno = 0; tno < 16; ++tno) {
        __syncthreads();   // prior tile's Ks reads done
#pragma unroll
        for (int p = 0; p < 3; ++p)
            *reinterpret_cast<uint4*>(&Ks[kr[p]][kc[p]]) = kreg[p];
        if (tno < 15) {
            const unsigned short* Kn = Kg + (size_t)(tno + 1) * 64 * 96;
#pragma unroll
            for (int p = 0; p < 3; ++p)
                kreg[p] = *reinterpret_cast<const uint4*>(&Kn[(size_t)kr[p] * 96 + kc[p]]);
        }
        __syncthreads();   // Ks(t) visible
        int mt = tno * MT;
        float sv[MT / 16][4];
#pragma unroll
        for (int nf = 0; nf < MT / 16; ++nf) {
            f32x4 acc = {};
#pragma unroll
            for (int kk = 0; kk < 3; ++kk) {
                s16x8 bb = ldf(&Ks[nf * 16 + lrow][kk * 32 + lkg * 8]);
                acc = __builtin_amdgcn_mfma_f32_16x16x32_bf16(qa[kk], bb, acc, 0, 0, 0);
            }
            float cv = colv[mt + nf * 16 + lrow];
#pragma unroll
            for (int r = 0; r < 4; ++r)
                sv[nf][r] = (rv[r] * cv != 0.f) ? acc[r] * scale : -1.0e6f;
        }
#pragma unroll
        for (int r = 0; r < 4; ++r) {
            float v = sv[0][r];
#pragma unroll
            for (int nf = 1; nf < MT / 16; ++nf) v = fmaxf(v, sv[nf][r]);
            for (int o = 1; o < 16; o <<= 1) v = fmaxf(v, __shfl_xor(v, o));
            float nm = fmaxf(mrun[r], v);
            float ts = 0.f;
#pragma unroll
            for (int nf = 0; nf < MT / 16; ++nf) ts += __expf(sv[nf][r] - nm);
            for (int o = 1; o < 16; o <<= 1) ts += __shfl_xor(ts, o);
            srun[r] = srun[r] * __expf(mrun[r] - nm) + ts;
            mrun[r] = nm;
        }
    }
    float sinv[4];
    for (int r = 0; r < 4; ++r) sinv[r] = 1.0f / srun[r];

    // ---- Pass B: prefetch K(t+1), V(t+1) under compute(t) ----
    uint4 vreg[3];
#pragma unroll
    for (int p = 0; p < 3; ++p) {
        kreg[p] = *reinterpret_cast<const uint4*>(&Kg[(size_t)kr[p] * 96 + kc[p]]);
        vreg[p] = *reinterpret_cast<const uint4*>(&Vg[(size_t)vr[p] * 1024 + vc[p]]);
    }

    f32x4 oacc[6] = {};
    for (int tno = 0; tno < 16; ++tno) {
        int mt = tno * MT;
        __syncthreads();   // prior tile's Ks/Vts reads done
#pragma unroll
        for (int p = 0; p < 3; ++p) {
            *reinterpret_cast<uint4*>(&Ks[kr[p]][kc[p]]) = kreg[p];
            *reinterpret_cast<uint4*>(&Vts[vr[p]][vc[p]]) = vreg[p];
        }
        if (tno < 15) {
            const unsigned short* Kn = Kg + (size_t)(tno + 1) * 64 * 96;
            int mn = mt + MT;
#pragma unroll
            for (int p = 0; p < 3; ++p) {
                kreg[p] = *reinterpret_cast<const uint4*>(&Kn[(size_t)kr[p] * 96 + kc[p]]);
                vreg[p] = *reinterpret_cast<const uint4*>(&Vg[(size_t)vr[p] * 1024 + mn + vc[p]]);
            }
        }
        __syncthreads();   // Ks/Vts(t) visible
#pragma unroll
        for (int nf = 0; nf < MT / 16; ++nf) {
            f32x4 acc = {};
#pragma unroll
            for (int kk = 0; kk < 3; ++kk) {
                s16x8 bb = ldf(&Ks[nf * 16 + lrow][kk * 32 + lkg * 8]);
                acc = __builtin_amdgcn_mfma_f32_16x16x32_bf16(qa[kk], bb, acc, 0, 0, 0);
            }
            float cv = colv[mt + nf * 16 + lrow];
#pragma unroll
            for (int r = 0; r < 4; ++r) {
                float sel = (rv[r] * cv != 0.f) ? acc[r] * scale : -1.0e6f;
                float p = __expf(sel - mrun[r]) * sinv[r];
                Ps[wid][lkg * 4 + r][nf * 16 + lrow] = f2bf(p);
            }
        }
        // Ps is wave-private: order ds_writes before ds_reads (rule 18)
        asm volatile("s_waitcnt lgkmcnt(0)" ::: "memory");
        __builtin_amdgcn_sched_barrier(0);
#pragma unroll
        for (int kk = 0; kk < MT / 32; ++kk) {
            s16x8 pa = ldf(&Ps[wid][lrow][kk * 32 + lkg * 8]);
#pragma unroll
            for (int df = 0; df < 6; ++df) {
                s16x8 vb = ldf(&Vts[df * 16 + lrow][kk * 32 + lkg * 8]);
                oacc[df] = __builtin_amdgcn_mfma_f32_16x16x32_bf16(pa, vb, oacc[df], 0, 0, 0);
            }
        }
        // coalesced attn_out write from Ps (bf16 -> fp32), 256B-contiguous per row
        {
            int r16 = lane >> 2, cb = (lane & 3) * 16;
            s16x8 pA = ldf(&Ps[wid][r16][cb]);
            s16x8 pB = ldf(&Ps[wid][r16][cb + 8]);
            float* dst = &attn_out[((size_t)bh * 256 + qrow0 + r16) * 1024 + mt + cb];
            float4 o0, o1, o2, o3;
            o0.x = bf2f((unsigned short)pA[0]); o0.y = bf2f((unsigned short)pA[1]);
            o0.z = bf2f((unsigned short)pA[2]); o0.w = bf2f((unsigned short)pA[3]);
            o1.x = bf2f((unsigned short)pA[4]); o1.y = bf2f((unsigned short)pA[5]);
            o1.z = bf2f((unsigned short)pA[6]); o1.w = bf2f((unsigned short)pA[7]);
            o2.x = bf2f((unsigned short)pB[0]); o2.y = bf2f((unsigned short)pB[1]);
            o2.z = bf2f((unsigned short)pB[2]); o2.w = bf2f((unsigned short)pB[3]);
            o3.x = bf2f((unsigned short)pB[4]); o3.y = bf2f((unsigned short)pB[5]);
            o3.z = bf2f((unsigned short)pB[6]); o3.w = bf2f((unsigned short)pB[7]);
            reinterpret_cast<float4*>(dst)[0] = o0;
            reinterpret_cast<float4*>(dst)[1] = o1;
            reinterpret_cast<float4*>(dst)[2] = o2;
            reinterpret_cast<float4*>(dst)[3] = o3;
        }
    }
    for (int df = 0; df < 6; ++df)
        for (int r = 0; r < 4; ++r) {
            int grow = b * 256 + qrow0 + lkg * 4 + r;
            int gcol = h * 96 + df * 16 + lrow;
            AO[(size_t)grow * 768 + gcol] = f2bf(oacc[df][r]);
        }
}

// ---------- residual + LayerNorm ----------
__global__ __launch_bounds__(256) void ln_kernel(
    const float* __restrict__ O, const float* __restrict__ drug,
    const float* __restrict__ bo, const float* __restrict__ gamma,
    const float* __restrict__ beta, float* __restrict__ out) {
    int row = blockIdx.x, tid = threadIdx.x;
    __shared__ float red[4];
    float x[3], s = 0.f;
    for (int i = 0; i < 3; ++i) {
        int j = tid + i * 256;
        x[i] = O[(size_t)row * 768 + j] + bo[j] + drug[(size_t)row * 768 + j];
        s += x[i];
    }
    for (int o = 32; o; o >>= 1) s += __shfl_xor(s, o);
    if ((tid & 63) == 0) red[tid >> 6] = s;
    __syncthreads();
    float mu = (red[0] + red[1] + red[2] + red[3]) * (1.0f / 768.0f);
    float v = 0.f;
    for (int i = 0; i < 3; ++i) { float d = x[i] - mu; v += d * d; }
    for (int o = 32; o; o >>= 1) v += __shfl_xor(v, o);
    __syncthreads();
    if ((tid & 63) == 0) red[tid >> 6] = v;
    __syncthreads();
    float var = (red[0] + red[1] + red[2] + red[3]) * (1.0f / 768.0f);
    float rs = rsqrtf(var + 1e-5f);
    for (int i = 0; i < 3; ++i) {
        int j = tid + i * 256;
        out[(size_t)row * 768 + j] = (x[i] - mu) * rs * gamma[j] + beta[j];
    }
}

extern "C" void kernel_launch(void* const* d_in, const int* in_sizes, int n_in,
                              void* d_out, int out_size, void* d_ws, size_t ws_size,
                              hipStream_t stream) {
    const float* drug   = (const float*)d_in[0];
    const float* target = (const float*)d_in[1];
    const int*   dmask  = (const int*)d_in[2];
    const int*   pmask  = (const int*)d_in[3];
    const float* Wq = (const float*)d_in[4];
    const float* Wk = (const float*)d_in[5];
    const float* Wv = (const float*)d_in[6];
    const float* Wo = (const float*)d_in[7];
    const float* bo = (const float*)d_in[8];
    const float* gm = (const float*)d_in[9];
    const float* bt = (const float*)d_in[10];

    char* w = (char*)d_ws;
    unsigned short* Wtq  = (unsigned short*)(w + 0);         // 768x768 bf16
    unsigned short* Wtkv = (unsigned short*)(w + 1179648);   // 1536x2560 bf16
    unsigned short* Wto  = (unsigned short*)(w + 9043968);   // 768x768 bf16
    unsigned short* Qb   = (unsigned short*)(w + 10223616);  // [128][256][96]
    unsigned short* Kb   = (unsigned short*)(w + 16515072);  // [128][1024][96]
    unsigned short* Vtb  = (unsigned short*)(w + 41680896);  // [128][96][1024]
    unsigned short* AO   = (unsigned short*)(w + 66846720);  // [4096][768]
    float*          Otmp = (float*)(w + 73138176);           // [4096][768] fp32
    unsigned short* drugb = (unsigned short*)(w + 85721088); // [4096][768] bf16

    float* out_ln   = (float*)d_out;
    float* attn_out = (float*)d_out + 3145728;
    // bf16 target parked in d_out's attn region (dead until attn_kernel rewrites it)
    unsigned short* targetb = (unsigned short*)attn_out;

    cvt_bf16_2<<<2560, 256, 0, stream>>>(target, targetb, 2048, 41943040,
                                         drug, drugb, 3145728);

    transpose2_bf16<<<dim3(24, 24, 2), 256, 0, stream>>>(Wq, Wo, Wtq, Wto, 768, 768);
    transpose2_bf16<<<dim3(80, 24, 2), 256, 0, stream>>>(
        Wk, Wv, Wtkv, Wtkv + (size_t)768 * 2560, 2560, 768);

    // KV GEMM: M=16384, N=1536, K=2560; 128 x 12 = 1536 blocks, 64 KB LDS, 2 blocks/CU
    gemm_db<1><<<1536, 256, 65536, stream>>>(targetb, Wtkv, 16384, 1536, 2560,
                                             nullptr, Kb, Vtb, 1024);
    // Q GEMM: M=4096, N=768, K=768
    gemm_db<1><<<192, 256, 65536, stream>>>(drugb, Wtq, 4096, 768, 768,
                                            nullptr, Qb, nullptr, 256);
    attn_kernel<<<dim3(128, 4), 256, 0, stream>>>(Qb, Kb, Vtb, dmask, pmask, attn_out, AO);
    // AO GEMM: M=4096, N=768, K=768
    gemm_db<0><<<192, 256, 65536, stream>>>(AO, Wto, 4096, 768, 768,
                                            Otmp, nullptr, nullptr, 256);
    ln_kernel<<<4096, 256, 0, stream>>>(Otmp, drug, bo, gm, bt, out_ln);
}

// Round 13
// 333.891 us; speedup vs baseline: 1.1212x; 1.1212x over previous
//
#include <hip/hip_runtime.h>

// ---------- types ----------
typedef short s16x8 __attribute__((ext_vector_type(8)));
typedef float f32x4 __attribute__((ext_vector_type(4)));

__device__ __forceinline__ unsigned short f2bf(float f) {
    unsigned int u = __builtin_bit_cast(unsigned int, f);
    unsigned int r = u + 0x7FFFu + ((u >> 16) & 1u);
    return (unsigned short)(r >> 16);
}

__device__ __forceinline__ void gload16(const unsigned short* g, unsigned short* l) {
    __builtin_amdgcn_global_load_lds(
        (const __attribute__((address_space(1))) unsigned int*)g,
        (__attribute__((address_space(3))) unsigned int*)l, 16, 0, 0);
}

__device__ __forceinline__ s16x8 ldf(const unsigned short* p) {
    return *reinterpret_cast<const s16x8*>(p);
}

// ---------- fp32 -> bf16, two arrays in one launch ----------
__global__ __launch_bounds__(256) void cvt_bf16_2(
    const float* __restrict__ in0, unsigned short* __restrict__ out0, int n0blk, int n0,
    const float* __restrict__ in1, unsigned short* __restrict__ out1, int n1) {
    const float* in;
    unsigned short* out;
    int n, bid;
    if (blockIdx.x < n0blk) { in = in0; out = out0; n = n0; bid = blockIdx.x; }
    else { in = in1; out = out1; n = n1; bid = blockIdx.x - n0blk; }
    int nblk = (blockIdx.x < n0blk) ? n0blk : (gridDim.x - n0blk);
    int i = (bid * 256 + threadIdx.x) * 8;
    int stride = nblk * 256 * 8;
    for (; i < n; i += stride) {
        float4 a = *reinterpret_cast<const float4*>(in + i);
        float4 b = *reinterpret_cast<const float4*>(in + i + 4);
        uint4 o;
        o.x = (unsigned int)f2bf(a.x) | ((unsigned int)f2bf(a.y) << 16);
        o.y = (unsigned int)f2bf(a.z) | ((unsigned int)f2bf(a.w) << 16);
        o.z = (unsigned int)f2bf(b.x) | ((unsigned int)f2bf(b.y) << 16);
        o.w = (unsigned int)f2bf(b.z) | ((unsigned int)f2bf(b.w) << 16);
        *reinterpret_cast<uint4*>(out + i) = o;
    }
}

// ---------- batched transpose + convert: Wt[n][k] = bf16(W[k][n]), 2 matrices ----------
__global__ __launch_bounds__(256) void transpose2_bf16(
    const float* __restrict__ W0, const float* __restrict__ W1,
    unsigned short* __restrict__ T0, unsigned short* __restrict__ T1, int K, int N) {
    __shared__ float t[32][33];
    const float* W = blockIdx.z ? W1 : W0;
    unsigned short* Wt = blockIdx.z ? T1 : T0;
    int k0 = blockIdx.x * 32, n0 = blockIdx.y * 32;
    int tid = threadIdx.x;
    int r = tid >> 5, c = tid & 31;
    for (int p = 0; p < 4; ++p)
        t[p * 8 + r][c] = W[(size_t)(k0 + p * 8 + r) * N + n0 + c];
    __syncthreads();
    for (int p = 0; p < 4; ++p)
        Wt[(size_t)(n0 + p * 8 + r) * K + k0 + c] = f2bf(t[c][p * 8 + r]);
}

// ---------- GEMM (proven): 128x128, BK=64, dbuf 2-phase ----------
// OUTMODE 1: scatter bf16 to attention layouts (K | Vt split at col 768).
// OUTMODE 0: fp32 C.
template <int OUTMODE>
__global__ __launch_bounds__(256, 2) void gemm_db(
    const unsigned short* __restrict__ A, const unsigned short* __restrict__ Bt,
    int M, int N, int K,
    float* __restrict__ Cf,
    unsigned short* __restrict__ outA, unsigned short* __restrict__ outVt,
    int seqlen) {
    extern __shared__ __align__(16) unsigned short smem[];
    unsigned short* As = smem;           // [2][128*64]
    unsigned short* Bs = smem + 16384;   // [2][128*64]

    int tid = threadIdx.x, wid = tid >> 6, lane = tid & 63;
    int nb = N / 128;
    int nwg = gridDim.x, bid = blockIdx.x;
    int wg = (bid & 7) * (nwg >> 3) + (bid >> 3);  // bijective XCD swizzle (nwg%8==0)
    int tm = wg / nb, tn = wg % nb;
    int m0 = tm * 128, n0 = tn * 128;
    int wm = (wid >> 1) * 64, wn = (wid & 1) * 64;
    int lrow = lane & 15, lkc = lane >> 4;

    // ---- staging addresses (global pre-swizzled, LDS linear) ----
    int lrsub = lane >> 3;               // row-in-8
    int gch = (lane & 7) ^ lrsub;        // swizzled source chunk
    const unsigned short* gA[4];
    const unsigned short* gB[4];
    unsigned short* lA[4];
    unsigned short* lB[4];
#pragma unroll
    for (int p = 0; p < 4; ++p) {
        int r = (wid * 4 + p) * 8 + lrsub;
        gA[p] = A + (size_t)(m0 + r) * K + gch * 8;
        gB[p] = Bt + (size_t)(n0 + r) * K + gch * 8;
        lA[p] = As + (wid * 4 + p) * 512;  // wave-uniform base; HW adds lane*16B
        lB[p] = Bs + (wid * 4 + p) * 512;
    }

    // ---- fragment ds_read offsets (swizzled), loop-invariant ----
    int offA[2][4], offB[2][4];
#pragma unroll
    for (int kh = 0; kh < 2; ++kh)
#pragma unroll
        for (int i = 0; i < 4; ++i) {
            int ra = wm + i * 16 + lrow;
            offA[kh][i] = ra * 64 + (((kh * 4 + lkc) ^ (ra & 7)) * 8);
            int rb = wn + i * 16 + lrow;
            offB[kh][i] = rb * 64 + (((kh * 4 + lkc) ^ (rb & 7)) * 8);
        }

    int NT = K / 64;
    f32x4 acc[4][4] = {};

    // prologue: stage tile 0 into buf 0
#pragma unroll
    for (int p = 0; p < 4; ++p) { gload16(gA[p], lA[p]); gload16(gB[p], lB[p]); }

    int cur = 0;
    for (int t = 0; t < NT; ++t) {
        __syncthreads();  // buf[cur] staged (vmcnt drained); prior reads of buf[cur^1] done
        if (t + 1 < NT) {
            int nxt = (cur ^ 1) * 8192;
            int koff = (t + 1) * 64;
#pragma unroll
            for (int p = 0; p < 4; ++p) {
                gload16(gA[p] + koff, lA[p] + nxt);
                gload16(gB[p] + koff, lB[p] + nxt);
            }
        }
        const unsigned short* Ab = As + cur * 8192;
        const unsigned short* Bb = Bs + cur * 8192;
#pragma unroll
        for (int kh = 0; kh < 2; ++kh) {
            s16x8 af[4], bfv[4];
#pragma unroll
            for (int i = 0; i < 4; ++i) af[i] = ldf(&Ab[offA[kh][i]]);
#pragma unroll
            for (int j = 0; j < 4; ++j) bfv[j] = ldf(&Bb[offB[kh][j]]);
#pragma unroll
            for (int i = 0; i < 4; ++i)
#pragma unroll
                for (int j = 0; j < 4; ++j)
                    acc[i][j] = __builtin_amdgcn_mfma_f32_16x16x32_bf16(af[i], bfv[j], acc[i][j], 0, 0, 0);
        }
        cur ^= 1;
    }

    // ---- epilogue ----
    int orow4 = (lane >> 4) * 4;
    int bblk = (OUTMODE == 1) ? (m0 / seqlen) : 0;
    for (int i = 0; i < 4; ++i)
        for (int j = 0; j < 4; ++j)
            for (int r = 0; r < 4; ++r) {
                int row = m0 + wm + i * 16 + orow4 + r;
                int col = n0 + wn + j * 16 + lrow;
                float v = acc[i][j][r];
                if constexpr (OUTMODE == 0) {
                    Cf[(size_t)row * N + col] = v;
                } else {
                    int s = row - bblk * seqlen;
                    unsigned short hv = f2bf(v);
                    if (col < 768) {
                        int h = col / 96, d = col - h * 96;
                        outA[(((size_t)(bblk * 8 + h)) * seqlen + s) * 96 + d] = hv;
                    } else {
                        int cc = col - 768;
                        int h = cc / 96, d = cc - h * 96;
                        outVt[(((size_t)(bblk * 8 + h)) * 96 + d) * seqlen + s] = hv;
                    }
                }
            }
}

// ---------- fused masked-softmax cross-attention (staged K/V — proven r11, minus Ps barrier) ----------
#define MT 64
__global__ __launch_bounds__(256) void attn_kernel(
    const unsigned short* __restrict__ Qb,   // [bh][256][96]
    const unsigned short* __restrict__ Kb,   // [bh][1024][96]
    const unsigned short* __restrict__ Vt,   // [bh][96][1024]
    const int* __restrict__ drug_mask,       // [16][256]
    const int* __restrict__ pro_mask,        // [16][1024]
    float* __restrict__ attn_out,            // [bh][256][1024]
    unsigned short* __restrict__ AO)         // [4096][768]
{
    constexpr float scale = 0.10206207261596575f;  // 96^-0.5
    __shared__ __align__(16) unsigned short Qs[64][104];
    __shared__ __align__(16) unsigned short Ks[MT][104];
    __shared__ __align__(16) unsigned short Vts[96][MT + 8];
    __shared__ __align__(16) unsigned short Ps[4][16][MT + 8];
    __shared__ float colv[1024];

    int tid = threadIdx.x, wid = tid >> 6, lane = tid & 63;
    int bh = blockIdx.x, nt = blockIdx.y;
    int b = bh >> 3, h = bh & 7;
    const unsigned short* Qg = Qb + (size_t)bh * 256 * 96 + (size_t)nt * 64 * 96;
    const unsigned short* Kg = Kb + (size_t)bh * 1024 * 96;
    const unsigned short* Vg = Vt + (size_t)bh * 96 * 1024;

    for (int idx = tid; idx < 64 * 12; idx += 256) {
        int r = idx / 12, s = idx % 12;
        *reinterpret_cast<uint4*>(&Qs[r][s * 8]) =
            *reinterpret_cast<const uint4*>(&Qg[r * 96 + s * 8]);
    }
    for (int m = tid; m < 1024; m += 256)
        colv[m] = (pro_mask[b * 1024 + m] != 0) ? 1.0f : 0.0f;

    int lrow = lane & 15, lkg = lane >> 4;
    int qrow0 = nt * 64 + wid * 16;
    float rv[4];
    for (int r = 0; r < 4; ++r)
        rv[r] = (drug_mask[b * 256 + qrow0 + lkg * 4 + r] != 0) ? 1.0f : 0.0f;

    __syncthreads();
    s16x8 qa[3];
    for (int kk = 0; kk < 3; ++kk)
        qa[kk] = ldf(&Qs[wid * 16 + lrow][kk * 32 + lkg * 8]);

    float mrun[4], srun[4];
    for (int r = 0; r < 4; ++r) { mrun[r] = -3.0e38f; srun[r] = 0.f; }

    // ---- Pass A: row max + sum (online) ----
    for (int mt = 0; mt < 1024; mt += MT) {
        __syncthreads();
        for (int idx = tid; idx < MT * 12; idx += 256) {
            int r = idx / 12, s = idx % 12;
            *reinterpret_cast<uint4*>(&Ks[r][s * 8]) =
                *reinterpret_cast<const uint4*>(&Kg[(size_t)(mt + r) * 96 + s * 8]);
        }
        __syncthreads();
        float sv[MT / 16][4];
        for (int nf = 0; nf < MT / 16; ++nf) {
            f32x4 acc = {};
            for (int kk = 0; kk < 3; ++kk) {
                s16x8 bb = ldf(&Ks[nf * 16 + lrow][kk * 32 + lkg * 8]);
                acc = __builtin_amdgcn_mfma_f32_16x16x32_bf16(qa[kk], bb, acc, 0, 0, 0);
            }
            float cv = colv[mt + nf * 16 + lrow];
            for (int r = 0; r < 4; ++r)
                sv[nf][r] = (rv[r] * cv != 0.f) ? acc[r] * scale : -1.0e6f;
        }
        for (int r = 0; r < 4; ++r) {
            float v = sv[0][r];
            for (int nf = 1; nf < MT / 16; ++nf) v = fmaxf(v, sv[nf][r]);
            for (int o = 1; o < 16; o <<= 1) v = fmaxf(v, __shfl_xor(v, o));
            float nm = fmaxf(mrun[r], v);
            float ts = 0.f;
            for (int nf = 0; nf < MT / 16; ++nf) ts += __expf(sv[nf][r] - nm);
            for (int o = 1; o < 16; o <<= 1) ts += __shfl_xor(ts, o);
            srun[r] = srun[r] * __expf(mrun[r] - nm) + ts;
            mrun[r] = nm;
        }
    }
    float sinv[4];
    for (int r = 0; r < 4; ++r) sinv[r] = 1.0f / srun[r];

    // ---- Pass B: recompute S, write attn, P @ V ----
    f32x4 oacc[6] = {};
    for (int mt = 0; mt < 1024; mt += MT) {
        __syncthreads();
        for (int idx = tid; idx < MT * 12; idx += 256) {
            int r = idx / 12, s = idx % 12;
            *reinterpret_cast<uint4*>(&Ks[r][s * 8]) =
                *reinterpret_cast<const uint4*>(&Kg[(size_t)(mt + r) * 96 + s * 8]);
        }
        for (int idx = tid; idx < 96 * (MT / 8); idx += 256) {
            int r = idx / (MT / 8), s = idx % (MT / 8);
            *reinterpret_cast<uint4*>(&Vts[r][s * 8]) =
                *reinterpret_cast<const uint4*>(&Vg[(size_t)r * 1024 + mt + s * 8]);
        }
        __syncthreads();
        for (int nf = 0; nf < MT / 16; ++nf) {
            f32x4 acc = {};
            for (int kk = 0; kk < 3; ++kk) {
                s16x8 bb = ldf(&Ks[nf * 16 + lrow][kk * 32 + lkg * 8]);
                acc = __builtin_amdgcn_mfma_f32_16x16x32_bf16(qa[kk], bb, acc, 0, 0, 0);
            }
            float cv = colv[mt + nf * 16 + lrow];
            for (int r = 0; r < 4; ++r) {
                float sel = (rv[r] * cv != 0.f) ? acc[r] * scale : -1.0e6f;
                float p = __expf(sel - mrun[r]) * sinv[r];
                attn_out[((size_t)bh * 256 + qrow0 + lkg * 4 + r) * 1024 + mt + nf * 16 + lrow] = p;
                Ps[wid][lkg * 4 + r][nf * 16 + lrow] = f2bf(p);
            }
        }
        // Ps is wave-private: order ds_writes before ds_reads without a block barrier (rule 18)
        asm volatile("s_waitcnt lgkmcnt(0)" ::: "memory");
        __builtin_amdgcn_sched_barrier(0);
        for (int kk = 0; kk < MT / 32; ++kk) {
            s16x8 pa = ldf(&Ps[wid][lrow][kk * 32 + lkg * 8]);
            for (int df = 0; df < 6; ++df) {
                s16x8 vb = ldf(&Vts[df * 16 + lrow][kk * 32 + lkg * 8]);
                oacc[df] = __builtin_amdgcn_mfma_f32_16x16x32_bf16(pa, vb, oacc[df], 0, 0, 0);
            }
        }
    }
    for (int df = 0; df < 6; ++df)
        for (int r = 0; r < 4; ++r) {
            int grow = b * 256 + qrow0 + lkg * 4 + r;
            int gcol = h * 96 + df * 16 + lrow;
            AO[(size_t)grow * 768 + gcol] = f2bf(oacc[df][r]);
        }
}

// ---------- residual + LayerNorm ----------
__global__ __launch_bounds__(256) void ln_kernel(
    const float* __restrict__ O, const float* __restrict__ drug,
    const float* __restrict__ bo, const float* __restrict__ gamma,
    const float* __restrict__ beta, float* __restrict__ out) {
    int row = blockIdx.x, tid = threadIdx.x;
    __shared__ float red[4];
    float x[3], s = 0.f;
    for (int i = 0; i < 3; ++i) {
        int j = tid + i * 256;
        x[i] = O[(size_t)row * 768 + j] + bo[j] + drug[(size_t)row * 768 + j];
        s += x[i];
    }
    for (int o = 32; o; o >>= 1) s += __shfl_xor(s, o);
    if ((tid & 63) == 0) red[tid >> 6] = s;
    __syncthreads();
    float mu = (red[0] + red[1] + red[2] + red[3]) * (1.0f / 768.0f);
    float v = 0.f;
    for (int i = 0; i < 3; ++i) { float d = x[i] - mu; v += d * d; }
    for (int o = 32; o; o >>= 1) v += __shfl_xor(v, o);
    __syncthreads();
    if ((tid & 63) == 0) red[tid >> 6] = v;
    __syncthreads();
    float var = (red[0] + red[1] + red[2] + red[3]) * (1.0f / 768.0f);
    float rs = rsqrtf(var + 1e-5f);
    for (int i = 0; i < 3; ++i) {
        int j = tid + i * 256;
        out[(size_t)row * 768 + j] = (x[i] - mu) * rs * gamma[j] + beta[j];
    }
}

extern "C" void kernel_launch(void* const* d_in, const int* in_sizes, int n_in,
                              void* d_out, int out_size, void* d_ws, size_t ws_size,
                              hipStream_t stream) {
    const float* drug   = (const float*)d_in[0];
    const float* target = (const float*)d_in[1];
    const int*   dmask  = (const int*)d_in[2];
    const int*   pmask  = (const int*)d_in[3];
    const float* Wq = (const float*)d_in[4];
    const float* Wk = (const float*)d_in[5];
    const float* Wv = (const float*)d_in[6];
    const float* Wo = (const float*)d_in[7];
    const float* bo = (const float*)d_in[8];
    const float* gm = (const float*)d_in[9];
    const float* bt = (const float*)d_in[10];

    char* w = (char*)d_ws;
    unsigned short* Wtq  = (unsigned short*)(w + 0);         // 768x768 bf16
    unsigned short* Wtkv = (unsigned short*)(w + 1179648);   // 1536x2560 bf16
    unsigned short* Wto  = (unsigned short*)(w + 9043968);   // 768x768 bf16
    unsigned short* Qb   = (unsigned short*)(w + 10223616);  // [128][256][96]
    unsigned short* Kb   = (unsigned short*)(w + 16515072);  // [128][1024][96]
    unsigned short* Vtb  = (unsigned short*)(w + 41680896);  // [128][96][1024]
    unsigned short* AO   = (unsigned short*)(w + 66846720);  // [4096][768]
    float*          Otmp = (float*)(w + 73138176);           // [4096][768] fp32
    unsigned short* drugb = (unsigned short*)(w + 85721088); // [4096][768] bf16

    float* out_ln   = (float*)d_out;
    float* attn_out = (float*)d_out + 3145728;
    // bf16 target parked in d_out's attn region (dead until attn_kernel rewrites it)
    unsigned short* targetb = (unsigned short*)attn_out;

    // fp32->bf16 for target (blocks 0..2047) and drug (blocks 2048..2559), one launch
    cvt_bf16_2<<<2560, 256, 0, stream>>>(target, targetb, 2048, 41943040,
                                         drug, drugb, 3145728);

    transpose2_bf16<<<dim3(24, 24, 2), 256, 0, stream>>>(Wq, Wo, Wtq, Wto, 768, 768);
    transpose2_bf16<<<dim3(80, 24, 2), 256, 0, stream>>>(
        Wk, Wv, Wtkv, Wtkv + (size_t)768 * 2560, 2560, 768);

    // KV GEMM: M=16384, N=1536, K=2560; 128 x 12 = 1536 blocks, 64 KB LDS, 2 blocks/CU
    gemm_db<1><<<1536, 256, 65536, stream>>>(targetb, Wtkv, 16384, 1536, 2560,
                                             nullptr, Kb, Vtb, 1024);
    // Q GEMM: M=4096, N=768, K=768; 32 x 6 = 192 blocks
    gemm_db<1><<<192, 256, 65536, stream>>>(drugb, Wtq, 4096, 768, 768,
                                            nullptr, Qb, nullptr, 256);
    attn_kernel<<<dim3(128, 4), 256, 0, stream>>>(Qb, Kb, Vtb, dmask, pmask, attn_out, AO);
    // AO GEMM: M=4096, N=768, K=768
    gemm_db<0><<<192, 256, 65536, stream>>>(AO, Wto, 4096, 768, 768,
                                            Otmp, nullptr, nullptr, 256);
    ln_kernel<<<4096, 256, 0, stream>>>(Otmp, drug, bo, gm, bt, out_ln);
}